// Round 9
// baseline (4606.853 us; speedup 1.0000x reference)
//
#include <hip/hip_runtime.h>
#include <stdint.h>

typedef unsigned short u16;
typedef short short8 __attribute__((ext_vector_type(8)));
typedef float f32x4 __attribute__((ext_vector_type(4)));
typedef int i32x4 __attribute__((ext_vector_type(4)));
typedef unsigned long long u64;

#define NT 512
#define NH 1024
#define G4H 4096
#define HS_ELEMS 33554432ull   // 64*512*1024

static __device__ __forceinline__ u16 f2bf(float f){
  union { float f; unsigned u; } v; v.f = f;
  unsigned r = v.u + 0x7fffu + ((v.u >> 16) & 1u);   // RNE
  return (u16)(r >> 16);
}
static __device__ __forceinline__ float bf2f(u16 s){
  union { unsigned u; float f; } v; v.u = ((unsigned)s) << 16;
  return v.f;
}

// ---------------- fp32 -> bf16 bulk convert ----------------
__global__ void cvt_kernel(const float* __restrict__ in, u16* __restrict__ out, int n8){
  int i = blockIdx.x*blockDim.x + threadIdx.x;
  int stride = gridDim.x*blockDim.x;
  for (; i < n8; i += stride){
    const float4* p = (const float4*)in;
    float4 a = p[2*i], b = p[2*i+1];
    short8 o;
    o[0]=(short)f2bf(a.x); o[1]=(short)f2bf(a.y); o[2]=(short)f2bf(a.z); o[3]=(short)f2bf(a.w);
    o[4]=(short)f2bf(b.x); o[5]=(short)f2bf(b.y); o[6]=(short)f2bf(b.z); o[7]=(short)f2bf(b.w);
    ((short8*)out)[i] = o;
  }
}

// ---------------- init h ring buffer + flags ----------------
__global__ void init_kernel(unsigned* __restrict__ hx, int* __restrict__ cnt){
  int i = blockIdx.x*blockDim.x + threadIdx.x;
  int stride = gridDim.x*blockDim.x;
  for (int k = i; k < 131072; k += stride) hx[k] = 0u;   // 512 KiB of bf16 zeros
  if (i < 256) cnt[i] = 0;
}

// ---------------- phase 1: xg = x @ w_ih^T + b  (bf16 MFMA, m97-style) ----------------
__global__ __launch_bounds__(256) void gemm_xg(
    const u16* __restrict__ A,     // x bf16 [32768][1024]
    const u16* __restrict__ Bw,    // w_ih bf16 [4096][1024]  (B^T layout)
    const float* __restrict__ bias,
    u16* __restrict__ C)           // xg bf16 [32768][4096]
{
  __shared__ u16 lA[128*64];
  __shared__ u16 lB[128*64];
  const int tid = threadIdx.x, lane = tid & 63, w = tid >> 6;
  int bid = blockIdx.x;
  int swz = (bid & 7)*1024 + (bid >> 3);     // XCD swizzle (8192 % 8 == 0, bijective)
  const int brow = swz >> 5;                 // 0..255
  const int bcol = swz & 31;                 // 0..31
  const int wr = (w >> 1)*64, wc = (w & 1)*64;
  f32x4 acc[4][4] = {};

  const int rA0 = brow*128 + w*32;
  const int rB0 = bcol*128 + w*32;
  for (int kt = 0; kt < 1024; kt += 64){
    const u16* gA = A  + (size_t)(rA0 + (lane>>3))*1024 + kt + (lane&7)*8;
    const u16* gB = Bw + (size_t)(rB0 + (lane>>3))*1024 + kt + (lane&7)*8;
#pragma unroll
    for (int c = 0; c < 4; c++){
      __builtin_amdgcn_global_load_lds(
        (const __attribute__((address_space(1))) void*)(gA + (size_t)c*8*1024),
        (__attribute__((address_space(3))) void*)&lA[(w*32 + c*8)*64], 16, 0, 0);
      __builtin_amdgcn_global_load_lds(
        (const __attribute__((address_space(1))) void*)(gB + (size_t)c*8*1024),
        (__attribute__((address_space(3))) void*)&lB[(w*32 + c*8)*64], 16, 0, 0);
    }
    __syncthreads();
#pragma unroll
    for (int kk = 0; kk < 2; kk++){
      short8 fa[4], fb[4];
#pragma unroll
      for (int i = 0; i < 4; i++){
        fa[i] = *(const short8*)&lA[(wr + i*16 + (lane&15))*64 + kk*32 + (lane>>4)*8];
        fb[i] = *(const short8*)&lB[(wc + i*16 + (lane&15))*64 + kk*32 + (lane>>4)*8];
      }
#pragma unroll
      for (int i = 0; i < 4; i++)
#pragma unroll
        for (int jj = 0; jj < 4; jj++)
          acc[i][jj] = __builtin_amdgcn_mfma_f32_16x16x32_bf16(fa[i], fb[jj], acc[i][jj], 0,0,0);
    }
    __syncthreads();
  }
  const int mb = brow*128 + wr + ((lane>>4)<<2);
  const int nb = bcol*128 + wc + (lane&15);
#pragma unroll
  for (int jj = 0; jj < 4; jj++){
    const int n = nb + jj*16;
    const float bv = bias[n];
#pragma unroll
    for (int i = 0; i < 4; i++){
#pragma unroll
      for (int reg = 0; reg < 4; reg++){
        int m = mb + i*16 + reg;
        C[(size_t)m*G4H + n] = f2bf(acc[i][jj][reg] + bv);
      }
    }
  }
}

// ---------------- phase 2: persistent recurrence (flag-based fence-free sync) ----------------
// Grid 256 = 4 batch-groups (16 rows) x 64 col-slice WGs (16 h-cols each).
// Compute core = R6/R8-proven (plain weight loads + builtin MFMA).
// Sync (R8 fence-free protocol, counter -> per-WG flags; zero RMW/contention):
//   writer: paired u32 relaxed agent stores (sc1 write-through) -> __syncthreads
//           (per-wave vmcnt(0): stores ACKED at coherence point) -> tid0 posts
//           flags[g][j] = t+1 (own 4B slot, relaxed store, no contention).
//   reader: wave 0 polls all 64 group flags in ONE coalesced load (lane i <-
//           flags[g][i], sc1), __all(f >= t) ballot, s_sleep backoff -> barrier
//           -> stage h via relaxed agent u64 loads -> LDS.
// Skew proof: entering step t requires all flags >= t => all finished t-1;
// concurrent steps span <= 1; ring depth 4 >= required 3 => race-free.
__global__ __launch_bounds__(256, 1) void lstm_rec(
    const u16* __restrict__ whh,   // [4096][1024] bf16
    const u16* __restrict__ xg,    // [64*512][4096] bf16 (row b*512+t), bias included
    u16* __restrict__ hx,          // [4][4][32][64][8] bf16 (fragment order)
    int* cnt,                      // [4][64] per-WG flags
    float* __restrict__ hs,
    float* __restrict__ cs)
{
  __shared__ u16 lds_h[16384];     // 32 KiB: group h in fragment order [32][64][8]
  const int tid  = threadIdx.x;
  const int lane = tid & 63;
  const int w    = tid >> 6;
  const int bid  = blockIdx.x;
  const int g    = bid >> 6;          // batch group 0..3
  const int j    = bid & 63;          // col-slice 0..63
  const int q    = (lane & 15) >> 2;  // gate type 0:i 1:f 2:g 3:o
  const int col  = j*16 + w*4 + (lane & 3);   // h column 0..1023
  const int Gr   = q*1024 + col;              // gate row 0..4095
  const int mloc = (lane >> 4) * 4;           // batch-in-group base

  // ---- weights -> regs (R6-proven; compiler parks them in AGPRs) ----
  i32x4 wq[32];
  {
    const i32x4* wp = (const i32x4*)(whh + (size_t)Gr*1024 + ((lane>>4)*8));
#pragma unroll
    for (int kk = 0; kk < 32; kk++) wq[kk] = wp[kk*4];
#pragma unroll
    for (int kk = 0; kk < 32; kk++) asm volatile("" : "+v"(wq[kk]));
  }

  float c_st[4] = {0.f,0.f,0.f,0.f};
  int* flagsg = cnt + g*64;

  for (int t = 0; t < NT; t++){
    // xg prefetch (independent of h) — hides HBM latency under the poll
    float xv[4];
#pragma unroll
    for (int reg = 0; reg < 4; reg++){
      int b = g*16 + mloc + reg;
      xv[reg] = bf2f(xg[((size_t)b*NT + t)*G4H + Gr]);
    }
    // ---- wait for h(t-1): wave 0 polls all 64 flags in one load ----
    if (t > 0){
      if (w == 0){
        for (;;){
          int f = __hip_atomic_load(flagsg + lane, __ATOMIC_RELAXED, __HIP_MEMORY_SCOPE_AGENT);
          if (__all(f >= t)) break;
          __builtin_amdgcn_s_sleep(1);
        }
      }
      __syncthreads();
    }
    // ---- stage h(t-1) -> LDS via sc1 atomic u64 loads (bypass stale L2) ----
    const u64* hb64 = (const u64*)(hx + ((size_t)(((t+3)&3)*4 + g)) * 16384);
#pragma unroll
    for (int k = 0; k < 16; k++){
      int W = tid + 256*k;
      u64 v = __hip_atomic_load(hb64 + W, __ATOMIC_RELAXED, __HIP_MEMORY_SCOPE_AGENT);
      *(u64*)&lds_h[W*4] = v;
    }
    __syncthreads();

    // ---- gates = xg + h @ w_hh^T : 32 builtin MFMAs ----
    f32x4 accv[4];
    accv[0] = (f32x4){xv[0], xv[1], xv[2], xv[3]};
    accv[1] = (f32x4){0.f,0.f,0.f,0.f};
    accv[2] = accv[1]; accv[3] = accv[1];
#pragma unroll
    for (int kk = 0; kk < 32; kk++){
      short8 av = *(const short8*)&lds_h[(kk*64 + lane)*8];
      short8 bv = __builtin_bit_cast(short8, wq[kk]);
      accv[kk & 3] = __builtin_amdgcn_mfma_f32_16x16x32_bf16(av, bv, accv[kk & 3], 0,0,0);
    }
    f32x4 gv = (accv[0] + accv[1]) + (accv[2] + accv[3]);

    // ---- activations + outputs + h publish ----
    u16* wbuf = hx + ((size_t)((t&3)*4 + g)) * 16384;
#pragma unroll
    for (int reg = 0; reg < 4; reg++){
      float xg_ = gv[reg];
      float sig = 1.f / (1.f + __expf(-xg_));
      float th  = 1.f - 2.f / (1.f + __expf(2.f*xg_));
      float a   = (q == 2) ? th : sig;
      float v4  = __shfl_xor(a, 4);
      float v8  = __shfl_xor(a, 8);
      float v12 = __shfl_xor(a, 12);
      float iv  = (q==0)?a :(q==1)?v4:(q==2)?v8:v12;
      float fv  = (q==1)?a :(q==0)?v4:(q==3)?v8:v12;
      float gg  = (q==2)?a :(q==3)?v4:(q==0)?v8:v12;
      float ov  = (q==3)?a :(q==2)?v4:(q==1)?v8:v12;
      float cn  = fv*c_st[reg] + iv*gg;
      c_st[reg] = cn;
      float tc  = 1.f - 2.f / (1.f + __expf(2.f*cn));
      float hn  = ov * tc;
      int b = g*16 + mloc + reg;
      size_t oidx = ((size_t)b*NT + t)*NH + col;
      if (q == 1) __builtin_nontemporal_store(hn, &hs[oidx]);
      if (q == 2) __builtin_nontemporal_store(cn, &cs[oidx]);
      // publish h via paired u32 sc1 atomic store (write-through to L3)
      float hp = __shfl_xor(hn, 1);          // partner column's h
      if (q == 0 && (lane & 1) == 0){
        unsigned word = (unsigned)f2bf(hn) | ((unsigned)f2bf(hp) << 16);
        int sub = ((col & 31) >> 3)*16 + (mloc + reg);
        int idx16 = ((col >> 5)*64 + sub)*8 + (col & 7);   // even
        __hip_atomic_store((unsigned*)(wbuf + idx16), word,
                           __ATOMIC_RELAXED, __HIP_MEMORY_SCOPE_AGENT);
      }
    }
    __syncthreads();   // per-wave vmcnt(0): all publish stores ACKED at L3
    if (tid == 0)
      __hip_atomic_store(flagsg + j, t + 1,
                         __ATOMIC_RELAXED, __HIP_MEMORY_SCOPE_AGENT);
  }
}

extern "C" void kernel_launch(void* const* d_in, const int* in_sizes, int n_in,
                              void* d_out, int out_size, void* d_ws, size_t ws_size,
                              hipStream_t stream){
  const float* x    = (const float*)d_in[0];
  const float* wih  = (const float*)d_in[1];
  const float* whh  = (const float*)d_in[2];
  const float* bias = (const float*)d_in[3];
  float* hs = (float*)d_out;
  float* cs = hs + HS_ELEMS;
  char* ws = (char*)d_ws;
  // ws layout (~337 MiB)
  u16* xg   = (u16*)(ws + 0);              // 256 MiB
  u16* xb   = (u16*)(ws + 268435456ull);   // 64 MiB
  u16* wihb = (u16*)(ws + 335544320ull);   // 8 MiB
  u16* whhb = (u16*)(ws + 343932928ull);   // 8 MiB
  u16* hx   = (u16*)(ws + 352321536ull);   // 512 KiB
  int* cnt  = (int*)(ws + 352845824ull);   // 1 KiB

  cvt_kernel<<<2048, 256, 0, stream>>>(x,   xb,   33554432/8);
  cvt_kernel<<<512,  256, 0, stream>>>(wih, wihb, 4194304/8);
  cvt_kernel<<<512,  256, 0, stream>>>(whh, whhb, 4194304/8);
  init_kernel<<<64,  256, 0, stream>>>((unsigned*)hx, cnt);
  gemm_xg<<<8192, 256, 0, stream>>>(xb, wihb, bias, xg);

  const u16* whhb_c = whhb; const u16* xg_c = xg;
  u16* hx_p = hx; int* cnt_p = cnt; float* hs_p = hs; float* cs_p = cs;
  void* args[6];
  args[0] = (void*)&whhb_c;
  args[1] = (void*)&xg_c;
  args[2] = (void*)&hx_p;
  args[3] = (void*)&cnt_p;
  args[4] = (void*)&hs_p;
  args[5] = (void*)&cs_p;
  hipLaunchCooperativeKernel((const void*)lstm_rec, dim3(256), dim3(256), args, 0, stream);
}

// Round 10
// 4379.846 us; speedup vs baseline: 1.0518x; 1.0518x over previous
//
#include <hip/hip_runtime.h>
#include <stdint.h>

typedef unsigned short u16;
typedef short short8 __attribute__((ext_vector_type(8)));
typedef float f32x4 __attribute__((ext_vector_type(4)));
typedef int i32x4 __attribute__((ext_vector_type(4)));
typedef unsigned long long u64;

#define NT 512
#define NH 1024
#define G4H 4096
#define HS_ELEMS 33554432ull   // 64*512*1024
#define SENT 0x7FC07FC07FC07FC0ull

static __device__ __forceinline__ u16 f2bf(float f){
  union { float f; unsigned u; } v; v.f = f;
  unsigned r = v.u + 0x7fffu + ((v.u >> 16) & 1u);   // RNE
  return (u16)(r >> 16);
}
static __device__ __forceinline__ float bf2f(u16 s){
  union { unsigned u; float f; } v; v.u = ((unsigned)s) << 16;
  return v.f;
}
// any 16-bit lane of v equal to 0x7FC0 -> nonzero result
static __device__ __forceinline__ u64 sent_bits(u64 v){
  u64 y = v ^ SENT;
  return (y - 0x0001000100010001ull) & ~y & 0x8000800080008000ull;
}

// ---------------- fp32 -> bf16 bulk convert ----------------
__global__ void cvt_kernel(const float* __restrict__ in, u16* __restrict__ out, int n8){
  int i = blockIdx.x*blockDim.x + threadIdx.x;
  int stride = gridDim.x*blockDim.x;
  for (; i < n8; i += stride){
    const float4* p = (const float4*)in;
    float4 a = p[2*i], b = p[2*i+1];
    short8 o;
    o[0]=(short)f2bf(a.x); o[1]=(short)f2bf(a.y); o[2]=(short)f2bf(a.z); o[3]=(short)f2bf(a.w);
    o[4]=(short)f2bf(b.x); o[5]=(short)f2bf(b.y); o[6]=(short)f2bf(b.z); o[7]=(short)f2bf(b.w);
    ((short8*)out)[i] = o;
  }
}

// ---------------- init h(-1) zero buffer ----------------
__global__ void init_kernel(unsigned* __restrict__ hx){
  int i = blockIdx.x*blockDim.x + threadIdx.x;
  int stride = gridDim.x*blockDim.x;
  for (int k = i; k < 8192; k += stride) hx[k] = 0u;   // 32 KiB zeros (one group slot)
}

// ---------------- sentinel-fill the 64 MiB step-buffer arena ----------------
__global__ void sent_kernel(u64* __restrict__ p){
  int i = blockIdx.x*blockDim.x + threadIdx.x;
  int stride = gridDim.x*blockDim.x;
  for (int k = i; k < 8388608; k += stride) p[k] = SENT;
}

// ---------------- phase 1: xg = x @ w_ih^T + b  (bf16 MFMA, m97-style) ----------------
__global__ __launch_bounds__(256) void gemm_xg(
    const u16* __restrict__ A,     // x bf16 [32768][1024]
    const u16* __restrict__ Bw,    // w_ih bf16 [4096][1024]  (B^T layout)
    const float* __restrict__ bias,
    u16* __restrict__ C)           // xg bf16 [32768][4096]
{
  __shared__ u16 lA[128*64];
  __shared__ u16 lB[128*64];
  const int tid = threadIdx.x, lane = tid & 63, w = tid >> 6;
  int bid = blockIdx.x;
  int swz = (bid & 7)*1024 + (bid >> 3);     // XCD swizzle (8192 % 8 == 0, bijective)
  const int brow = swz >> 5;                 // 0..255
  const int bcol = swz & 31;                 // 0..31
  const int wr = (w >> 1)*64, wc = (w & 1)*64;
  f32x4 acc[4][4] = {};

  const int rA0 = brow*128 + w*32;
  const int rB0 = bcol*128 + w*32;
  for (int kt = 0; kt < 1024; kt += 64){
    const u16* gA = A  + (size_t)(rA0 + (lane>>3))*1024 + kt + (lane&7)*8;
    const u16* gB = Bw + (size_t)(rB0 + (lane>>3))*1024 + kt + (lane&7)*8;
#pragma unroll
    for (int c = 0; c < 4; c++){
      __builtin_amdgcn_global_load_lds(
        (const __attribute__((address_space(1))) void*)(gA + (size_t)c*8*1024),
        (__attribute__((address_space(3))) void*)&lA[(w*32 + c*8)*64], 16, 0, 0);
      __builtin_amdgcn_global_load_lds(
        (const __attribute__((address_space(1))) void*)(gB + (size_t)c*8*1024),
        (__attribute__((address_space(3))) void*)&lB[(w*32 + c*8)*64], 16, 0, 0);
    }
    __syncthreads();
#pragma unroll
    for (int kk = 0; kk < 2; kk++){
      short8 fa[4], fb[4];
#pragma unroll
      for (int i = 0; i < 4; i++){
        fa[i] = *(const short8*)&lA[(wr + i*16 + (lane&15))*64 + kk*32 + (lane>>4)*8];
        fb[i] = *(const short8*)&lB[(wc + i*16 + (lane&15))*64 + kk*32 + (lane>>4)*8];
      }
#pragma unroll
      for (int i = 0; i < 4; i++)
#pragma unroll
        for (int jj = 0; jj < 4; jj++)
          acc[i][jj] = __builtin_amdgcn_mfma_f32_16x16x32_bf16(fa[i], fb[jj], acc[i][jj], 0,0,0);
    }
    __syncthreads();
  }
  const int mb = brow*128 + wr + ((lane>>4)<<2);
  const int nb = bcol*128 + wc + (lane&15);
#pragma unroll
  for (int jj = 0; jj < 4; jj++){
    const int n = nb + jj*16;
    const float bv = bias[n];
#pragma unroll
    for (int i = 0; i < 4; i++){
#pragma unroll
      for (int reg = 0; reg < 4; reg++){
        int m = mb + i*16 + reg;
        C[(size_t)m*G4H + n] = f2bf(acc[i][jj][reg] + bv);
      }
    }
  }
}

// ---------------- phase 2: persistent recurrence (sentinel data-flow sync) ----------------
// Grid 256 = 4 batch-groups (16 rows) x 64 col-slice WGs (16 h-cols each).
// Compute core = R6/R8-proven (plain weight loads + builtin MFMA, weights
// parked in AGPRs by the compiler).
// Sync: NO flags, NO fences, NO publish-ack. Every step t owns a unique
// 32KB/group buffer hxbig[t][g], sentinel-prefilled (bf16 NaN 0x7FC0 —
// unproducible by f2bf of h in (-1,1)). Writer: posted sc1 u32 stores.
// Reader: batch-issue 16 sc1 u64 loads, validate sentinel bits, retry only
// late words — consumes data as it arrives. Each u32 transitions
// sentinel->final atomically; u64 tearing is detected and retried; no ABA.
// WAR-free by construction (buffers never rewritten).
// One barrier/step + double-buffered LDS (2x32KB): the barrier's implicit
// vmcnt(0) only drains acks already returned during the prior compute phase.
__global__ __launch_bounds__(256, 1) void lstm_rec(
    const u16* __restrict__ whh,   // [4096][1024] bf16
    const u16* __restrict__ xg,    // [64*512][4096] bf16 (row b*512+t), bias included
    u16* __restrict__ hxbig,       // [512][4][32][64][8] bf16 (fragment order)
    const u16* __restrict__ hz,    // 32 KiB zeros (h(-1), any group)
    float* __restrict__ hs,
    float* __restrict__ cs)
{
  __shared__ u16 lds_h[2][16384];  // 2 x 32 KiB: group h in fragment order [32][64][8]
  const int tid  = threadIdx.x;
  const int lane = tid & 63;
  const int w    = tid >> 6;
  const int bid  = blockIdx.x;
  const int g    = bid >> 6;          // batch group 0..3
  const int j    = bid & 63;          // col-slice 0..63
  const int q    = (lane & 15) >> 2;  // gate type 0:i 1:f 2:g 3:o
  const int col  = j*16 + w*4 + (lane & 3);   // h column 0..1023
  const int Gr   = q*1024 + col;              // gate row 0..4095
  const int mloc = (lane >> 4) * 4;           // batch-in-group base

  // ---- weights -> regs (R6-proven; compiler parks them in AGPRs) ----
  i32x4 wq[32];
  {
    const i32x4* wp = (const i32x4*)(whh + (size_t)Gr*1024 + ((lane>>4)*8));
#pragma unroll
    for (int kk = 0; kk < 32; kk++) wq[kk] = wp[kk*4];
#pragma unroll
    for (int kk = 0; kk < 32; kk++) asm volatile("" : "+v"(wq[kk]));
  }

  float c_st[4] = {0.f,0.f,0.f,0.f};

  for (int t = 0; t < NT; t++){
    // xg prefetch (independent of h)
    float xv[4];
#pragma unroll
    for (int reg = 0; reg < 4; reg++){
      int b = g*16 + mloc + reg;
      xv[reg] = bf2f(xg[((size_t)b*NT + t)*G4H + Gr]);
    }
    // ---- stage h(t-1): batch sc1 loads, sentinel-validate, retry late words ----
    const u64* hb64 = (t == 0) ? (const u64*)hz
                    : (const u64*)(hxbig + ((size_t)(t-1)*4 + g) * 16384);
    u64 vv[16];
#pragma unroll
    for (int k = 0; k < 16; k++)
      vv[k] = __hip_atomic_load(hb64 + tid + 256*k, __ATOMIC_RELAXED, __HIP_MEMORY_SCOPE_AGENT);
    u64 bad = 0;
#pragma unroll
    for (int k = 0; k < 16; k++) bad |= sent_bits(vv[k]);
    if (__builtin_expect(bad != 0, 0)){
#pragma unroll
      for (int k = 0; k < 16; k++){
        while (sent_bits(vv[k])){
          __builtin_amdgcn_s_sleep(1);
          vv[k] = __hip_atomic_load(hb64 + tid + 256*k, __ATOMIC_RELAXED, __HIP_MEMORY_SCOPE_AGENT);
        }
      }
    }
    u16* ldsb = &lds_h[t & 1][0];
#pragma unroll
    for (int k = 0; k < 16; k++)
      *(u64*)&ldsb[(tid + 256*k)*4] = vv[k];
    __syncthreads();   // the only barrier per step (LDS visibility; dbuf handles WAR)

    // ---- gates = xg + h @ w_hh^T : 32 builtin MFMAs ----
    f32x4 accv[4];
    accv[0] = (f32x4){xv[0], xv[1], xv[2], xv[3]};
    accv[1] = (f32x4){0.f,0.f,0.f,0.f};
    accv[2] = accv[1]; accv[3] = accv[1];
#pragma unroll
    for (int kk = 0; kk < 32; kk++){
      short8 av = *(const short8*)&ldsb[(kk*64 + lane)*8];
      short8 bv = __builtin_bit_cast(short8, wq[kk]);
      accv[kk & 3] = __builtin_amdgcn_mfma_f32_16x16x32_bf16(av, bv, accv[kk & 3], 0,0,0);
    }
    f32x4 gv = (accv[0] + accv[1]) + (accv[2] + accv[3]);

    // ---- activations + outputs + h publish (posted, no ack) ----
    u16* wbuf = hxbig + ((size_t)t*4 + g) * 16384;
#pragma unroll
    for (int reg = 0; reg < 4; reg++){
      float xg_ = gv[reg];
      float sig = 1.f / (1.f + __expf(-xg_));
      float th  = 1.f - 2.f / (1.f + __expf(2.f*xg_));
      float a   = (q == 2) ? th : sig;
      float v4  = __shfl_xor(a, 4);
      float v8  = __shfl_xor(a, 8);
      float v12 = __shfl_xor(a, 12);
      float iv  = (q==0)?a :(q==1)?v4:(q==2)?v8:v12;
      float fv  = (q==1)?a :(q==0)?v4:(q==3)?v8:v12;
      float gg  = (q==2)?a :(q==3)?v4:(q==0)?v8:v12;
      float ov  = (q==3)?a :(q==2)?v4:(q==1)?v8:v12;
      float cn  = fv*c_st[reg] + iv*gg;
      c_st[reg] = cn;
      float tc  = 1.f - 2.f / (1.f + __expf(2.f*cn));
      float hn  = ov * tc;
      int b = g*16 + mloc + reg;
      size_t oidx = ((size_t)b*NT + t)*NH + col;
      if (q == 1) __builtin_nontemporal_store(hn, &hs[oidx]);
      if (q == 2) __builtin_nontemporal_store(cn, &cs[oidx]);
      float hp = __shfl_xor(hn, 1);          // partner column's h
      if (q == 0 && (lane & 1) == 0){
        unsigned word = (unsigned)f2bf(hn) | ((unsigned)f2bf(hp) << 16);
        int sub = ((col & 31) >> 3)*16 + (mloc + reg);
        int idx16 = ((col >> 5)*64 + sub)*8 + (col & 7);   // even
        __hip_atomic_store((unsigned*)(wbuf + idx16), word,
                           __ATOMIC_RELAXED, __HIP_MEMORY_SCOPE_AGENT);
      }
    }
    // no end-of-step barrier, no ack: sentinel protocol + LDS dbuf cover it
  }
}

extern "C" void kernel_launch(void* const* d_in, const int* in_sizes, int n_in,
                              void* d_out, int out_size, void* d_ws, size_t ws_size,
                              hipStream_t stream){
  const float* x    = (const float*)d_in[0];
  const float* wih  = (const float*)d_in[1];
  const float* whh  = (const float*)d_in[2];
  const float* bias = (const float*)d_in[3];
  float* hs = (float*)d_out;
  float* cs = hs + HS_ELEMS;
  char* ws = (char*)d_ws;
  // ws layout (~337 MiB)
  u16* xg    = (u16*)(ws + 0);              // 256 MiB
  u16* xb    = (u16*)(ws + 268435456ull);   // 64 MiB (x bf16; DEAD after gemm)
  u16* hxbig = xb;                          // 64 MiB step-buffer arena (reuses xb)
  u16* wihb  = (u16*)(ws + 335544320ull);   // 8 MiB
  u16* whhb  = (u16*)(ws + 343932928ull);   // 8 MiB
  u16* hz    = (u16*)(ws + 352321536ull);   // 32 KiB zeros (h(-1))

  cvt_kernel<<<2048, 256, 0, stream>>>(x,   xb,   33554432/8);
  cvt_kernel<<<512,  256, 0, stream>>>(wih, wihb, 4194304/8);
  cvt_kernel<<<512,  256, 0, stream>>>(whh, whhb, 4194304/8);
  init_kernel<<<32,  256, 0, stream>>>((unsigned*)hz);
  gemm_xg<<<8192, 256, 0, stream>>>(xb, wihb, bias, xg);
  sent_kernel<<<4096, 256, 0, stream>>>((u64*)hxbig);   // after gemm: xb is dead

  const u16* whhb_c = whhb; const u16* xg_c = xg; const u16* hz_c = hz;
  u16* hxbig_p = hxbig; float* hs_p = hs; float* cs_p = cs;
  void* args[6];
  args[0] = (void*)&whhb_c;
  args[1] = (void*)&xg_c;
  args[2] = (void*)&hxbig_p;
  args[3] = (void*)&hz_c;
  args[4] = (void*)&hs_p;
  args[5] = (void*)&cs_p;
  hipLaunchCooperativeKernel((const void*)lstm_rec, dim3(256), dim3(256), args, 0, stream);
}

// Round 14
// 3877.607 us; speedup vs baseline: 1.1881x; 1.1295x over previous
//
#include <hip/hip_runtime.h>
#include <stdint.h>

typedef unsigned short u16;
typedef short short8 __attribute__((ext_vector_type(8)));
typedef float f32x4 __attribute__((ext_vector_type(4)));
typedef int i32x4 __attribute__((ext_vector_type(4)));
typedef unsigned long long u64;

#define NT 512
#define NH 1024
#define G4H 4096
#define HS_ELEMS 33554432ull   // 64*512*1024

static __device__ __forceinline__ u16 f2bf(float f){
  union { float f; unsigned u; } v; v.f = f;
  unsigned r = v.u + 0x7fffu + ((v.u >> 16) & 1u);   // RNE
  return (u16)(r >> 16);
}
static __device__ __forceinline__ float bf2f(u16 s){
  union { unsigned u; float f; } v; v.u = ((unsigned)s) << 16;
  return v.f;
}

// ---------------- fp32 -> bf16 bulk convert ----------------
__global__ void cvt_kernel(const float* __restrict__ in, u16* __restrict__ out, int n8){
  int i = blockIdx.x*blockDim.x + threadIdx.x;
  int stride = gridDim.x*blockDim.x;
  for (; i < n8; i += stride){
    const float4* p = (const float4*)in;
    float4 a = p[2*i], b = p[2*i+1];
    short8 o;
    o[0]=(short)f2bf(a.x); o[1]=(short)f2bf(a.y); o[2]=(short)f2bf(a.z); o[3]=(short)f2bf(a.w);
    o[4]=(short)f2bf(b.x); o[5]=(short)f2bf(b.y); o[6]=(short)f2bf(b.z); o[7]=(short)f2bf(b.w);
    ((short8*)out)[i] = o;
  }
}

// ---------------- init h ring buffer + counters ----------------
__global__ void init_kernel(unsigned* __restrict__ hx, int* __restrict__ cnt){
  int i = blockIdx.x*blockDim.x + threadIdx.x;
  int stride = gridDim.x*blockDim.x;
  for (int k = i; k < 131072; k += stride) hx[k] = 0u;   // 512 KiB of bf16 zeros
  if (i < 256) cnt[i] = 0;
}

// ---------------- phase 1: xg = x @ w_ih^T + b  (bf16 MFMA, m97-style) ----------------
__global__ __launch_bounds__(256) void gemm_xg(
    const u16* __restrict__ A,     // x bf16 [32768][1024]
    const u16* __restrict__ Bw,    // w_ih bf16 [4096][1024]  (B^T layout)
    const float* __restrict__ bias,
    u16* __restrict__ C)           // xg bf16 [32768][4096]
{
  __shared__ u16 lA[128*64];
  __shared__ u16 lB[128*64];
  const int tid = threadIdx.x, lane = tid & 63, w = tid >> 6;
  int bid = blockIdx.x;
  int swz = (bid & 7)*1024 + (bid >> 3);     // XCD swizzle (8192 % 8 == 0, bijective)
  const int brow = swz >> 5;                 // 0..255
  const int bcol = swz & 31;                 // 0..31
  const int wr = (w >> 1)*64, wc = (w & 1)*64;
  f32x4 acc[4][4] = {};

  const int rA0 = brow*128 + w*32;
  const int rB0 = bcol*128 + w*32;
  for (int kt = 0; kt < 1024; kt += 64){
    const u16* gA = A  + (size_t)(rA0 + (lane>>3))*1024 + kt + (lane&7)*8;
    const u16* gB = Bw + (size_t)(rB0 + (lane>>3))*1024 + kt + (lane&7)*8;
#pragma unroll
    for (int c = 0; c < 4; c++){
      __builtin_amdgcn_global_load_lds(
        (const __attribute__((address_space(1))) void*)(gA + (size_t)c*8*1024),
        (__attribute__((address_space(3))) void*)&lA[(w*32 + c*8)*64], 16, 0, 0);
      __builtin_amdgcn_global_load_lds(
        (const __attribute__((address_space(1))) void*)(gB + (size_t)c*8*1024),
        (__attribute__((address_space(3))) void*)&lB[(w*32 + c*8)*64], 16, 0, 0);
    }
    __syncthreads();
#pragma unroll
    for (int kk = 0; kk < 2; kk++){
      short8 fa[4], fb[4];
#pragma unroll
      for (int i = 0; i < 4; i++){
        fa[i] = *(const short8*)&lA[(wr + i*16 + (lane&15))*64 + kk*32 + (lane>>4)*8];
        fb[i] = *(const short8*)&lB[(wc + i*16 + (lane&15))*64 + kk*32 + (lane>>4)*8];
      }
#pragma unroll
      for (int i = 0; i < 4; i++)
#pragma unroll
        for (int jj = 0; jj < 4; jj++)
          acc[i][jj] = __builtin_amdgcn_mfma_f32_16x16x32_bf16(fa[i], fb[jj], acc[i][jj], 0,0,0);
    }
    __syncthreads();
  }
  const int mb = brow*128 + wr + ((lane>>4)<<2);
  const int nb = bcol*128 + wc + (lane&15);
#pragma unroll
  for (int jj = 0; jj < 4; jj++){
    const int n = nb + jj*16;
    const float bv = bias[n];
#pragma unroll
    for (int i = 0; i < 4; i++){
#pragma unroll
      for (int reg = 0; reg < 4; reg++){
        int m = mb + i*16 + reg;
        C[(size_t)m*G4H + n] = f2bf(acc[i][jj][reg] + bv);
      }
    }
  }
}

// ---------------- phase 2: persistent recurrence (R8 protocol + deferred outputs) ----------------
// Grid 256 = 4 batch-groups (16 rows) x 64 col-slice WGs (16 h-cols each).
// Compute core + protocol = R8 (PASSED, 3.51ms), byte-identical except:
//  (a) hs/cs output stores DEFERRED until after the signal — the pre-signal
//      barrier drains only the 2 small sc1 publish stores; the HBM output
//      acks drain at the NEXT step's barrier, hidden under poll/stage/compute.
//  (b) poll cadence s_sleep(2) -> s_sleep(1) (halved detect granularity).
// R8 protocol (sound: EVERY WG polls EVERY step, so the cumulative counter
// proves per-step completion — the R13 lesson):
//   writer: paired u32 relaxed agent stores (sc1 write-through) ->
//           __syncthreads (per-wave vmcnt(0): publishes ACKED) -> tid0
//           relaxed fetch_add.
//   reader: tid0 relaxed poll (s_sleep backoff) -> barrier -> stage h via
//           relaxed agent u64 loads (sc1) -> LDS.
// Ring depth 4; cnt>=64t gating bounds skew <= 1 step => race-free.
__global__ __launch_bounds__(256, 1) void lstm_rec(
    const u16* __restrict__ whh,   // [4096][1024] bf16
    const u16* __restrict__ xg,    // [64*512][4096] bf16 (row b*512+t), bias included
    u16* __restrict__ hx,          // [4][4][32][64][8] bf16 (fragment order)
    int* cnt,                      // [4*64] (256B-spaced per group)
    float* __restrict__ hs,
    float* __restrict__ cs)
{
  __shared__ u16 lds_h[16384];     // 32 KiB: group h in fragment order [32][64][8]
  const int tid  = threadIdx.x;
  const int lane = tid & 63;
  const int w    = tid >> 6;
  const int bid  = blockIdx.x;
  const int g    = bid >> 6;          // batch group 0..3
  const int j    = bid & 63;          // col-slice 0..63
  const int q    = (lane & 15) >> 2;  // gate type 0:i 1:f 2:g 3:o
  const int col  = j*16 + w*4 + (lane & 3);   // h column 0..1023
  const int Gr   = q*1024 + col;              // gate row 0..4095
  const int mloc = (lane >> 4) * 4;           // batch-in-group base

  // ---- weights -> regs (R6-proven; compiler parks them in AGPRs) ----
  i32x4 wq[32];
  {
    const i32x4* wp = (const i32x4*)(whh + (size_t)Gr*1024 + ((lane>>4)*8));
#pragma unroll
    for (int kk = 0; kk < 32; kk++) wq[kk] = wp[kk*4];
#pragma unroll
    for (int kk = 0; kk < 32; kk++) asm volatile("" : "+v"(wq[kk]));
  }

  float c_st[4] = {0.f,0.f,0.f,0.f};
  int* cntg = cnt + g*64;

  for (int t = 0; t < NT; t++){
    // xg prefetch (independent of h) — hides HBM latency under the poll
    float xv[4];
#pragma unroll
    for (int reg = 0; reg < 4; reg++){
      int b = g*16 + mloc + reg;
      xv[reg] = bf2f(xg[((size_t)b*NT + t)*G4H + Gr]);
    }
    // ---- wait for h(t-1): leader relaxed poll -> barrier (NO fence) ----
    if (t > 0){
      if (tid == 0){
        const int need = t * 64;
        while (__hip_atomic_load(cntg, __ATOMIC_RELAXED, __HIP_MEMORY_SCOPE_AGENT) < need)
          __builtin_amdgcn_s_sleep(1);
      }
      __syncthreads();
    }
    // ---- stage h(t-1) -> LDS via sc1 atomic u64 loads (bypass stale L2) ----
    const u64* hb64 = (const u64*)(hx + ((size_t)(((t+3)&3)*4 + g)) * 16384);
#pragma unroll
    for (int k = 0; k < 16; k++){
      int W = tid + 256*k;
      u64 v = __hip_atomic_load(hb64 + W, __ATOMIC_RELAXED, __HIP_MEMORY_SCOPE_AGENT);
      *(u64*)&lds_h[W*4] = v;
    }
    __syncthreads();

    // ---- gates = xg + h @ w_hh^T : 32 builtin MFMAs ----
    f32x4 accv[4];
    accv[0] = (f32x4){xv[0], xv[1], xv[2], xv[3]};
    accv[1] = (f32x4){0.f,0.f,0.f,0.f};
    accv[2] = accv[1]; accv[3] = accv[1];
#pragma unroll
    for (int kk = 0; kk < 32; kk++){
      short8 av = *(const short8*)&lds_h[(kk*64 + lane)*8];
      short8 bv = __builtin_bit_cast(short8, wq[kk]);
      accv[kk & 3] = __builtin_amdgcn_mfma_f32_16x16x32_bf16(av, bv, accv[kk & 3], 0,0,0);
    }
    f32x4 gv = (accv[0] + accv[1]) + (accv[2] + accv[3]);

    // ---- activations; publish h, ack, signal, THEN deferred output stores ----
    u16* wbuf = hx + ((size_t)((t&3)*4 + g)) * 16384;
    float hnv[4], cnv[4];
#pragma unroll
    for (int reg = 0; reg < 4; reg++){
      float xg_ = gv[reg];
      float sig = 1.f / (1.f + __expf(-xg_));
      float th  = 1.f - 2.f / (1.f + __expf(2.f*xg_));
      float a   = (q == 2) ? th : sig;
      float v4  = __shfl_xor(a, 4);
      float v8  = __shfl_xor(a, 8);
      float v12 = __shfl_xor(a, 12);
      float iv  = (q==0)?a :(q==1)?v4:(q==2)?v8:v12;
      float fv  = (q==1)?a :(q==0)?v4:(q==3)?v8:v12;
      float gg  = (q==2)?a :(q==3)?v4:(q==0)?v8:v12;
      float ov  = (q==3)?a :(q==2)?v4:(q==1)?v8:v12;
      float cn  = fv*c_st[reg] + iv*gg;
      c_st[reg] = cn;
      float tc  = 1.f - 2.f / (1.f + __expf(2.f*cn));
      float hn  = ov * tc;
      hnv[reg] = hn; cnv[reg] = cn;
      // publish h via paired u32 sc1 atomic store (write-through to L3)
      float hp = __shfl_xor(hn, 1);          // partner column's h
      if (q == 0 && (lane & 1) == 0){
        unsigned word = (unsigned)f2bf(hn) | ((unsigned)f2bf(hp) << 16);
        int sub = ((col & 31) >> 3)*16 + (mloc + reg);
        int idx16 = ((col >> 5)*64 + sub)*8 + (col & 7);   // even
        __hip_atomic_store((unsigned*)(wbuf + idx16), word,
                           __ATOMIC_RELAXED, __HIP_MEMORY_SCOPE_AGENT);
      }
    }
    __syncthreads();   // drains ONLY the publish stores (outputs not yet issued)
    if (tid == 0)
      __hip_atomic_fetch_add(cntg, 1, __ATOMIC_RELAXED, __HIP_MEMORY_SCOPE_AGENT);
    // deferred output stores — off the signal path; acks drain next step
#pragma unroll
    for (int reg = 0; reg < 4; reg++){
      int b = g*16 + mloc + reg;
      size_t oidx = ((size_t)b*NT + t)*NH + col;
      if (q == 1) __builtin_nontemporal_store(hnv[reg], &hs[oidx]);
      if (q == 2) __builtin_nontemporal_store(cnv[reg], &cs[oidx]);
    }
  }
}

extern "C" void kernel_launch(void* const* d_in, const int* in_sizes, int n_in,
                              void* d_out, int out_size, void* d_ws, size_t ws_size,
                              hipStream_t stream){
  const float* x    = (const float*)d_in[0];
  const float* wih  = (const float*)d_in[1];
  const float* whh  = (const float*)d_in[2];
  const float* bias = (const float*)d_in[3];
  float* hs = (float*)d_out;
  float* cs = hs + HS_ELEMS;
  char* ws = (char*)d_ws;
  // ws layout (~337 MiB)
  u16* xg   = (u16*)(ws + 0);              // 256 MiB
  u16* xb   = (u16*)(ws + 268435456ull);   // 64 MiB
  u16* wihb = (u16*)(ws + 335544320ull);   // 8 MiB
  u16* whhb = (u16*)(ws + 343932928ull);   // 8 MiB
  u16* hx   = (u16*)(ws + 352321536ull);   // 512 KiB
  int* cnt  = (int*)(ws + 352845824ull);   // 1 KiB

  cvt_kernel<<<2048, 256, 0, stream>>>(x,   xb,   33554432/8);
  cvt_kernel<<<512,  256, 0, stream>>>(wih, wihb, 4194304/8);
  cvt_kernel<<<512,  256, 0, stream>>>(whh, whhb, 4194304/8);
  init_kernel<<<64,  256, 0, stream>>>((unsigned*)hx, cnt);
  gemm_xg<<<8192, 256, 0, stream>>>(xb, wihb, bias, xg);

  const u16* whhb_c = whhb; const u16* xg_c = xg;
  u16* hx_p = hx; int* cnt_p = cnt; float* hs_p = hs; float* cs_p = cs;
  void* args[6];
  args[0] = (void*)&whhb_c;
  args[1] = (void*)&xg_c;
  args[2] = (void*)&hx_p;
  args[3] = (void*)&cnt_p;
  args[4] = (void*)&hs_p;
  args[5] = (void*)&cs_p;
  hipLaunchCooperativeKernel((const void*)lstm_rec, dim3(256), dim3(256), args, 0, stream);
}

// Round 17
// 3859.157 us; speedup vs baseline: 1.1937x; 1.0048x over previous
//
#include <hip/hip_runtime.h>
#include <stdint.h>

typedef unsigned short u16;
typedef short short8 __attribute__((ext_vector_type(8)));
typedef float f32x4 __attribute__((ext_vector_type(4)));
typedef int i32x4 __attribute__((ext_vector_type(4)));
typedef unsigned long long u64;

#define NT 512
#define NH 1024
#define G4H 4096
#define HS_ELEMS 33554432ull   // 64*512*1024

static __device__ __forceinline__ u16 f2bf(float f){
  union { float f; unsigned u; } v; v.f = f;
  unsigned r = v.u + 0x7fffu + ((v.u >> 16) & 1u);   // RNE
  return (u16)(r >> 16);
}
static __device__ __forceinline__ float bf2f(u16 s){
  union { unsigned u; float f; } v; v.u = ((unsigned)s) << 16;
  return v.f;
}

// ---------------- fp32 -> bf16 bulk convert ----------------
__global__ void cvt_kernel(const float* __restrict__ in, u16* __restrict__ out, int n8){
  int i = blockIdx.x*blockDim.x + threadIdx.x;
  int stride = gridDim.x*blockDim.x;
  for (; i < n8; i += stride){
    const float4* p = (const float4*)in;
    float4 a = p[2*i], b = p[2*i+1];
    short8 o;
    o[0]=(short)f2bf(a.x); o[1]=(short)f2bf(a.y); o[2]=(short)f2bf(a.z); o[3]=(short)f2bf(a.w);
    o[4]=(short)f2bf(b.x); o[5]=(short)f2bf(b.y); o[6]=(short)f2bf(b.z); o[7]=(short)f2bf(b.w);
    ((short8*)out)[i] = o;
  }
}

// ---------------- init h ring buffer + subcounters ----------------
__global__ void init_kernel(unsigned* __restrict__ hx, int* __restrict__ cnt){
  int i = blockIdx.x*blockDim.x + threadIdx.x;
  int stride = gridDim.x*blockDim.x;
  for (int k = i; k < 131072; k += stride) hx[k] = 0u;   // 512 KiB of bf16 zeros
  for (int k = i; k < 2048; k += stride) cnt[k] = 0;     // 4 groups x 8 subcounters (spaced)
}

// ---------------- phase 1: xg = x @ w_ih^T + b  (bf16 MFMA, m97-style) ----------------
__global__ __launch_bounds__(256) void gemm_xg(
    const u16* __restrict__ A,     // x bf16 [32768][1024]
    const u16* __restrict__ Bw,    // w_ih bf16 [4096][1024]  (B^T layout)
    const float* __restrict__ bias,
    u16* __restrict__ C)           // xg bf16 [32768][4096]
{
  __shared__ u16 lA[128*64];
  __shared__ u16 lB[128*64];
  const int tid = threadIdx.x, lane = tid & 63, w = tid >> 6;
  int bid = blockIdx.x;
  int swz = (bid & 7)*1024 + (bid >> 3);     // XCD swizzle (8192 % 8 == 0, bijective)
  const int brow = swz >> 5;                 // 0..255
  const int bcol = swz & 31;                 // 0..31
  const int wr = (w >> 1)*64, wc = (w & 1)*64;
  f32x4 acc[4][4] = {};

  const int rA0 = brow*128 + w*32;
  const int rB0 = bcol*128 + w*32;
  for (int kt = 0; kt < 1024; kt += 64){
    const u16* gA = A  + (size_t)(rA0 + (lane>>3))*1024 + kt + (lane&7)*8;
    const u16* gB = Bw + (size_t)(rB0 + (lane>>3))*1024 + kt + (lane&7)*8;
#pragma unroll
    for (int c = 0; c < 4; c++){
      __builtin_amdgcn_global_load_lds(
        (const __attribute__((address_space(1))) void*)(gA + (size_t)c*8*1024),
        (__attribute__((address_space(3))) void*)&lA[(w*32 + c*8)*64], 16, 0, 0);
      __builtin_amdgcn_global_load_lds(
        (const __attribute__((address_space(1))) void*)(gB + (size_t)c*8*1024),
        (__attribute__((address_space(3))) void*)&lB[(w*32 + c*8)*64], 16, 0, 0);
    }
    __syncthreads();
#pragma unroll
    for (int kk = 0; kk < 2; kk++){
      short8 fa[4], fb[4];
#pragma unroll
      for (int i = 0; i < 4; i++){
        fa[i] = *(const short8*)&lA[(wr + i*16 + (lane&15))*64 + kk*32 + (lane>>4)*8];
        fb[i] = *(const short8*)&lB[(wc + i*16 + (lane&15))*64 + kk*32 + (lane>>4)*8];
      }
#pragma unroll
      for (int i = 0; i < 4; i++)
#pragma unroll
        for (int jj = 0; jj < 4; jj++)
          acc[i][jj] = __builtin_amdgcn_mfma_f32_16x16x32_bf16(fa[i], fb[jj], acc[i][jj], 0,0,0);
    }
    __syncthreads();
  }
  const int mb = brow*128 + wr + ((lane>>4)<<2);
  const int nb = bcol*128 + wc + (lane&15);
#pragma unroll
  for (int jj = 0; jj < 4; jj++){
    const int n = nb + jj*16;
    const float bv = bias[n];
#pragma unroll
    for (int i = 0; i < 4; i++){
#pragma unroll
      for (int reg = 0; reg < 4; reg++){
        int m = mb + i*16 + reg;
        C[(size_t)m*G4H + n] = f2bf(acc[i][jj][reg] + bv);
      }
    }
  }
}

// ---------------- phase 2: persistent recurrence (R14 + 8-way split counter) ----------------
// Grid 256 = 4 batch-groups (16 rows) x 64 col-slice WGs (16 h-cols each).
// Base = R14 (PASSED, 3.36ms). ONLY change: the per-group signal counter is
// split into 8 subcounters 256B apart (different L3 banks). Writer j signals
// sub[j&7] (8 same-address RMWs per subcounter per step instead of 64 on one
// address — removes L3 bank serialization). Reader: wave 0 lanes 0..7 poll
// the 8 subcounters in one scattered load per round; __all(sub >= 8t).
// Soundness: first WG to enter t+1 needs all subs = 8(t+1) => all 64 WGs
// completed step t — induction identical to the single counter (R8/R14).
// Publish-visibility unchanged: signal issued AFTER the publish-ack barrier;
// stage reads start after detect + barrier (the empirically-robust ordering).
__global__ __launch_bounds__(256, 1) void lstm_rec(
    const u16* __restrict__ whh,   // [4096][1024] bf16
    const u16* __restrict__ xg,    // [64*512][4096] bf16 (row b*512+t), bias included
    u16* __restrict__ hx,          // [4][4][32][64][8] bf16 (fragment order)
    int* cnt,                      // [4][8 x 64-int-spaced] subcounters
    float* __restrict__ hs,
    float* __restrict__ cs)
{
  __shared__ u16 lds_h[16384];     // 32 KiB: group h in fragment order [32][64][8]
  const int tid  = threadIdx.x;
  const int lane = tid & 63;
  const int w    = tid >> 6;
  const int bid  = blockIdx.x;
  const int g    = bid >> 6;          // batch group 0..3
  const int j    = bid & 63;          // col-slice 0..63
  const int q    = (lane & 15) >> 2;  // gate type 0:i 1:f 2:g 3:o
  const int col  = j*16 + w*4 + (lane & 3);   // h column 0..1023
  const int Gr   = q*1024 + col;              // gate row 0..4095
  const int mloc = (lane >> 4) * 4;           // batch-in-group base

  // ---- weights -> regs (R6-proven; compiler parks them in AGPRs) ----
  i32x4 wq[32];
  {
    const i32x4* wp = (const i32x4*)(whh + (size_t)Gr*1024 + ((lane>>4)*8));
#pragma unroll
    for (int kk = 0; kk < 32; kk++) wq[kk] = wp[kk*4];
#pragma unroll
    for (int kk = 0; kk < 32; kk++) asm volatile("" : "+v"(wq[kk]));
  }

  float c_st[4] = {0.f,0.f,0.f,0.f};
  int* cntg = cnt + g*512;             // 8 subcounters at cntg[0,64,128,...,448]

  for (int t = 0; t < NT; t++){
    // xg prefetch (independent of h) — hides HBM latency under the poll
    float xv[4];
#pragma unroll
    for (int reg = 0; reg < 4; reg++){
      int b = g*16 + mloc + reg;
      xv[reg] = bf2f(xg[((size_t)b*NT + t)*G4H + Gr]);
    }
    // ---- wait for h(t-1): wave 0 polls 8 subcounters -> barrier ----
    if (t > 0){
      if (w == 0){
        const int need = t * 8;
        for (;;){
          int v = need;
          if (lane < 8)
            v = __hip_atomic_load(cntg + lane*64, __ATOMIC_RELAXED, __HIP_MEMORY_SCOPE_AGENT);
          if (__all(v >= need)) break;
          __builtin_amdgcn_s_sleep(1);
        }
      }
      __syncthreads();
    }
    // ---- stage h(t-1) -> LDS via sc1 atomic u64 loads (bypass stale L2) ----
    const u64* hb64 = (const u64*)(hx + ((size_t)(((t+3)&3)*4 + g)) * 16384);
#pragma unroll
    for (int k = 0; k < 16; k++){
      int W = tid + 256*k;
      u64 v = __hip_atomic_load(hb64 + W, __ATOMIC_RELAXED, __HIP_MEMORY_SCOPE_AGENT);
      *(u64*)&lds_h[W*4] = v;
    }
    __syncthreads();

    // ---- gates = xg + h @ w_hh^T : 32 builtin MFMAs ----
    f32x4 accv[4];
    accv[0] = (f32x4){xv[0], xv[1], xv[2], xv[3]};
    accv[1] = (f32x4){0.f,0.f,0.f,0.f};
    accv[2] = accv[1]; accv[3] = accv[1];
#pragma unroll
    for (int kk = 0; kk < 32; kk++){
      short8 av = *(const short8*)&lds_h[(kk*64 + lane)*8];
      short8 bv = __builtin_bit_cast(short8, wq[kk]);
      accv[kk & 3] = __builtin_amdgcn_mfma_f32_16x16x32_bf16(av, bv, accv[kk & 3], 0,0,0);
    }
    f32x4 gv = (accv[0] + accv[1]) + (accv[2] + accv[3]);

    // ---- activations; publish h, ack, signal, THEN deferred output stores ----
    u16* wbuf = hx + ((size_t)((t&3)*4 + g)) * 16384;
    float hnv[4], cnv[4];
#pragma unroll
    for (int reg = 0; reg < 4; reg++){
      float xg_ = gv[reg];
      float sig = 1.f / (1.f + __expf(-xg_));
      float th  = 1.f - 2.f / (1.f + __expf(2.f*xg_));
      float a   = (q == 2) ? th : sig;
      float v4  = __shfl_xor(a, 4);
      float v8  = __shfl_xor(a, 8);
      float v12 = __shfl_xor(a, 12);
      float iv  = (q==0)?a :(q==1)?v4:(q==2)?v8:v12;
      float fv  = (q==1)?a :(q==0)?v4:(q==3)?v8:v12;
      float gg  = (q==2)?a :(q==3)?v4:(q==0)?v8:v12;
      float ov  = (q==3)?a :(q==2)?v4:(q==1)?v8:v12;
      float cn  = fv*c_st[reg] + iv*gg;
      c_st[reg] = cn;
      float tc  = 1.f - 2.f / (1.f + __expf(2.f*cn));
      float hn  = ov * tc;
      hnv[reg] = hn; cnv[reg] = cn;
      // publish h via paired u32 sc1 atomic store (write-through to L3)
      float hp = __shfl_xor(hn, 1);          // partner column's h
      if (q == 0 && (lane & 1) == 0){
        unsigned word = (unsigned)f2bf(hn) | ((unsigned)f2bf(hp) << 16);
        int sub = ((col & 31) >> 3)*16 + (mloc + reg);
        int idx16 = ((col >> 5)*64 + sub)*8 + (col & 7);   // even
        __hip_atomic_store((unsigned*)(wbuf + idx16), word,
                           __ATOMIC_RELAXED, __HIP_MEMORY_SCOPE_AGENT);
      }
    }
    __syncthreads();   // drains ONLY the publish stores (outputs not yet issued)
    if (tid == 0)
      __hip_atomic_fetch_add(cntg + (j & 7)*64, 1,
                             __ATOMIC_RELAXED, __HIP_MEMORY_SCOPE_AGENT);
    // deferred output stores — off the signal path; acks drain next step
#pragma unroll
    for (int reg = 0; reg < 4; reg++){
      int b = g*16 + mloc + reg;
      size_t oidx = ((size_t)b*NT + t)*NH + col;
      if (q == 1) __builtin_nontemporal_store(hnv[reg], &hs[oidx]);
      if (q == 2) __builtin_nontemporal_store(cnv[reg], &cs[oidx]);
    }
  }
}

extern "C" void kernel_launch(void* const* d_in, const int* in_sizes, int n_in,
                              void* d_out, int out_size, void* d_ws, size_t ws_size,
                              hipStream_t stream){
  const float* x    = (const float*)d_in[0];
  const float* wih  = (const float*)d_in[1];
  const float* whh  = (const float*)d_in[2];
  const float* bias = (const float*)d_in[3];
  float* hs = (float*)d_out;
  float* cs = hs + HS_ELEMS;
  char* ws = (char*)d_ws;
  // ws layout (~337 MiB)
  u16* xg   = (u16*)(ws + 0);              // 256 MiB
  u16* xb   = (u16*)(ws + 268435456ull);   // 64 MiB
  u16* wihb = (u16*)(ws + 335544320ull);   // 8 MiB
  u16* whhb = (u16*)(ws + 343932928ull);   // 8 MiB
  u16* hx   = (u16*)(ws + 352321536ull);   // 512 KiB ring
  int* cnt  = (int*)(ws + 352845824ull);   // 8 KiB subcounters

  cvt_kernel<<<2048, 256, 0, stream>>>(x,   xb,   33554432/8);
  cvt_kernel<<<512,  256, 0, stream>>>(wih, wihb, 4194304/8);
  cvt_kernel<<<512,  256, 0, stream>>>(whh, whhb, 4194304/8);
  init_kernel<<<64,  256, 0, stream>>>((unsigned*)hx, cnt);
  gemm_xg<<<8192, 256, 0, stream>>>(xb, wihb, bias, xg);

  const u16* whhb_c = whhb; const u16* xg_c = xg;
  u16* hx_p = hx; int* cnt_p = cnt; float* hs_p = hs; float* cs_p = cs;
  void* args[6];
  args[0] = (void*)&whhb_c;
  args[1] = (void*)&xg_c;
  args[2] = (void*)&hx_p;
  args[3] = (void*)&cnt_p;
  args[4] = (void*)&hs_p;
  args[5] = (void*)&cs_p;
  hipLaunchCooperativeKernel((const void*)lstm_rec, dim3(256), dim3(256), args, 0, stream);
}